// Round 10
// baseline (198.093 us; speedup 1.0000x reference)
//
#include <hip/hip_runtime.h>

// VQ nearest-codebook: MFMA bf16 hi/lo filter + exact fp32-emulated rescore.
// R10: (1) vq_main barrier-FREE — B-frags double-buffered in REGISTERS
//      (8 x dwordx4 prefetch of chunk c+1 issued before compute of chunk c),
//      wave = 64 rows x 32 codes (537 MB L2 traffic), no LDS in the K-loop;
//      (2) rescore: block-per-vector, x staged in LDS, 4 ILP chains/thread,
//      packed-u64 argmin (numpy first-index ties for free).
//
// ref semantics (verified R2/R3/R6/R8/R9): d[n,k] = fl(fl(sx+se) - chain),
// sx/se = numpy pairwise-8 tree of squares, chain = sequential FMA over d of
// (2x)*e, argmin first-index tie-break. Ambiguous rows (packed gap <= 2^17
// ~ 3.05e-5) get the exact fp32-emulated rescore.

#define D 64
#define K 1024
#define HW 4096
#define NTOTAL 131072

// workspace layout (bytes)
#define BF_OFF   0          // B-frags: 32 chunks * 8 frags * 64 lanes * 16B = 256 KB
#define SE_OFF   262144     // 4 KB
#define CNT_OFF  266240
#define LIST_OFF 266244
#define LIST_CAP 65536
#define WS_NEED  (266244 + LIST_CAP * 4)

// packed-gap margin: 2^17 packed units = 3.05e-5 value gap (covers 2 ref fp32
// roundings at |sx+se|<128, bf16 3-term approx <1e-5, packing quantization).
#define MARGIN_P 131072u

typedef __attribute__((ext_vector_type(8))) short bf16x8;   // 8 bf16 = 4 VGPR
typedef __attribute__((ext_vector_type(4))) float f32x4;

__device__ __forceinline__ unsigned short bf16_rne(float f) {
    unsigned u = __float_as_uint(f);
    u += 0x7fffu + ((u >> 16) & 1u);
    return (unsigned short)(u >> 16);
}
__device__ __forceinline__ float bf16_to_f(unsigned short h) {
    return __uint_as_float(((unsigned)h) << 16);
}

// numpy pairwise sum, n=64: 8 accumulators + ((r0+r1)+(r2+r3))+((r4+r5)+(r6+r7))
__device__ __forceinline__ float np_sumsq64(const float* v) {
    float r[8];
#pragma unroll
    for (int j = 0; j < 8; ++j) r[j] = __fmul_rn(v[j], v[j]);
#pragma unroll
    for (int i = 8; i < 64; i += 8)
#pragma unroll
        for (int j = 0; j < 8; ++j)
            r[j] = __fadd_rn(r[j], __fmul_rn(v[i + j], v[i + j]));
    float s01 = __fadd_rn(r[0], r[1]), s23 = __fadd_rn(r[2], r[3]);
    float s45 = __fadd_rn(r[4], r[5]), s67 = __fadd_rn(r[6], r[7]);
    return __fadd_rn(__fadd_rn(s01, s23), __fadd_rn(s45, s67));
}

// --- prep: codebook -> se + B-frags in lane order; zeroes CNT ---
__global__ __launch_bounds__(256) void prep_cb(const float* __restrict__ cb,
                                               char* __restrict__ ws) {
    if (blockIdx.x == 0 && threadIdx.x == 0) *(int*)(ws + CNT_OFF) = 0;
    int k = blockIdx.x * 256 + threadIdx.x;          // grid 4*256 = 1024
    const float* e = cb + k * D;
    float v[D];
#pragma unroll
    for (int d = 0; d < D; ++d) v[d] = e[d];
    ((float*)(ws + SE_OFF))[k] = np_sumsq64(v);
    unsigned short hh[D], ll[D];
#pragma unroll
    for (int d = 0; d < D; ++d) {
        hh[d] = bf16_rne(v[d]);
        ll[d] = bf16_rne(v[d] - bf16_to_f(hh[d]));
    }
    const int c = k >> 5, tc = (k >> 4) & 1, c16 = k & 15;
    uint4* bf = (uint4*)(ws + BF_OFF);
#pragma unroll
    for (int qd = 0; qd < 8; ++qd) {                 // d0 = qd*8
        int q = qd & 3, jh = qd >> 2;
        int l = q * 16 + c16;
        uint4 a, b;
        const unsigned short* h = hh + qd * 8;
        const unsigned short* lo = ll + qd * 8;
        a.x = h[0] | (h[1] << 16);  a.y = h[2] | (h[3] << 16);
        a.z = h[4] | (h[5] << 16);  a.w = h[6] | (h[7] << 16);
        b.x = lo[0] | (lo[1] << 16); b.y = lo[2] | (lo[3] << 16);
        b.z = lo[4] | (lo[5] << 16); b.w = lo[6] | (lo[7] << 16);
        bf[(c * 8 + tc * 4 + jh) * 64 + l]       = a;   // hi -> j=jh
        bf[(c * 8 + tc * 4 + 2 + jh) * 64 + l]   = b;   // lo -> j=2+jh
    }
}

// --- main: barrier-free K-loop, register double-buffered B ---
// block = 256 threads = 4 waves; 256 rows/block (grid 512). Wave w owns rows
// w*64 + tv*16 + c16, tv=0..3. Chunk = 32 codes (tc=0..1).
__global__ __launch_bounds__(256, 2) void vq_main(const float* __restrict__ in,
                                                  const float* __restrict__ cb,
                                                  float* __restrict__ out,
                                                  char* __restrict__ ws) {
    __shared__ int s_widx[256];

    const int t = threadIdx.x;
    const int nb = blockIdx.x * 256;          // grid 512; 256 | 4096 -> same b
    const int b = nb >> 12, hw0 = nb & (HW - 1);
    const int lane = t & 63, q = lane >> 4, c16 = lane & 15, w = t >> 6;

    // ---- A-frags from global, fragment layout. A = -(2x), RNE hi/lo split.
    bf16x8 af[4][4];
#pragma unroll
    for (int tv = 0; tv < 4; ++tv) {
        const float* xp = in + (size_t)b * (D * HW) + hw0 + w * 64 + tv * 16 + c16;
        unsigned short h[16], l[16];
#pragma unroll
        for (int jh = 0; jh < 2; ++jh)
#pragma unroll
            for (int i = 0; i < 8; ++i) {
                float x = xp[(size_t)(jh * 32 + q * 8 + i) * HW];
                float ny = __fmul_rn(x, -2.0f);              // exact
                unsigned short nh = bf16_rne(ny);
                h[jh * 8 + i] = nh;
                l[jh * 8 + i] = bf16_rne(__fsub_rn(ny, bf16_to_f(nh)));
            }
#pragma unroll
        for (int jh = 0; jh < 2; ++jh) {
            bf16x8 vh, vl;
#pragma unroll
            for (int i = 0; i < 8; ++i) { vh[i] = (short)h[jh * 8 + i]; vl[i] = (short)l[jh * 8 + i]; }
            af[tv][jh]     = vh;     // j=0,1: hi
            af[tv][2 + jh] = vl;     // j=2,3: lo
        }
    }

    const float* seg = (const float*)(ws + SE_OFF);
    const uint4* bfp = (const uint4*)(ws + BF_OFF);

    unsigned p1[16], p2[16];
#pragma unroll
    for (int s = 0; s < 16; ++s) { p1[s] = 0xFFFFFFFFu; p2[s] = 0xFFFFFFFFu; }

    const int sa[6] = {0, 1, 2, 3, 0, 1};
    const int sb[6] = {0, 1, 0, 1, 2, 3};

    auto compute = [&](const uint4* buf, int c) {
        float sec0 = __fadd_rn(seg[c * 32 + c16], 1.5f);
        float sec1 = __fadd_rn(seg[c * 32 + 16 + c16], 1.5f);
        f32x4 acc[4][2];
#pragma unroll
        for (int tv = 0; tv < 4; ++tv) {
            acc[tv][0] = (f32x4){sec0, sec0, sec0, sec0};
            acc[tv][1] = (f32x4){sec1, sec1, sec1, sec1};
        }
#pragma unroll
        for (int s = 0; s < 6; ++s)
#pragma unroll
            for (int tv = 0; tv < 4; ++tv)
#pragma unroll
                for (int tc = 0; tc < 2; ++tc)
                    acc[tv][tc] = __builtin_amdgcn_mfma_f32_16x16x32_bf16(
                        af[tv][sa[s]], *(const bf16x8*)&buf[tc * 4 + sb[s]],
                        acc[tv][tc], 0, 0, 0);
        // acc = (se+1.5) - dot in [1.33,1.67] -> IEEE bits value-monotone.
        // p = ((bits>>1)<<10)|code -> ties break to lower code (numpy).
#pragma unroll
        for (int tv = 0; tv < 4; ++tv)
#pragma unroll
            for (int tc = 0; tc < 2; ++tc) {
                unsigned code = (unsigned)(c * 32 + tc * 16 + c16);
#pragma unroll
                for (int r = 0; r < 4; ++r) {
                    unsigned u = __float_as_uint(acc[tv][tc][r]);
                    unsigned p = ((u >> 1) << 10) | code;
                    int s = tv * 4 + r;
                    unsigned mx = p > p1[s] ? p : p1[s];
                    p2[s] = mx < p2[s] ? mx : p2[s];
                    p1[s] = p < p1[s] ? p : p1[s];
                }
            }
    };

    // ---- register double-buffered, barrier-free K-loop
    uint4 bufA[8], bufB[8];
#pragma unroll
    for (int j = 0; j < 8; ++j) bufA[j] = bfp[j * 64 + lane];
    for (int c = 0; c < 32; c += 2) {
#pragma unroll
        for (int j = 0; j < 8; ++j) bufB[j] = bfp[((c + 1) * 8 + j) * 64 + lane];
        compute(bufA, c);
        if (c + 2 < 32) {
#pragma unroll
            for (int j = 0; j < 8; ++j) bufA[j] = bfp[((c + 2) * 8 + j) * 64 + lane];
        }
        compute(bufB, c + 1);
    }

    // ---- cross-lane top-2 merge over the 16 col-lanes
#pragma unroll
    for (int m = 1; m < 16; m <<= 1)
#pragma unroll
        for (int s = 0; s < 16; ++s) {
            unsigned o1 = (unsigned)__shfl_xor((int)p1[s], m, 64);
            unsigned o2 = (unsigned)__shfl_xor((int)p2[s], m, 64);
            unsigned lo = p1[s] < o1 ? p1[s] : o1;
            unsigned hi = p1[s] < o1 ? o1 : p1[s];
            unsigned n2 = p2[s] < o2 ? p2[s] : o2;
            p2[s] = hi < n2 ? hi : n2;
            p1[s] = lo;
        }

    if (c16 == 0) {
#pragma unroll
        for (int s = 0; s < 16; ++s) {
            int tv = s >> 2, r = s & 3;
            int row = w * 64 + tv * 16 + q * 4 + r;    // block-local 0..255
            s_widx[row] = (int)(p1[s] & 1023u);
            if (p2[s] - p1[s] <= MARGIN_P) {
                int pos = atomicAdd((int*)(ws + CNT_OFF), 1);
                if (pos < LIST_CAP) ((int*)(ws + LIST_OFF))[pos] = nb + row;
            }
        }
    }
    __syncthreads();

    // ---- gather-write: thread t owns row t (stores coalesced across threads)
    {
        int widx = s_widx[t];
        const float4* er = (const float4*)(cb + (size_t)widx * D);
        float* op = out + (size_t)b * (D * HW) + hw0 + t;
#pragma unroll
        for (int i = 0; i < 16; ++i) {
            float4 v = er[i];
            op[(size_t)(i * 4 + 0) * HW] = v.x;
            op[(size_t)(i * 4 + 1) * HW] = v.y;
            op[(size_t)(i * 4 + 2) * HW] = v.z;
            op[(size_t)(i * 4 + 3) * HW] = v.w;
        }
    }
}

// --- rescore: block-per-vector exact fp32-emulated scan, 4 ILP chains/thread ---
__global__ __launch_bounds__(256) void vq_rescore(const float* __restrict__ in,
                                                  const float* __restrict__ cb,
                                                  float* __restrict__ out,
                                                  char* __restrict__ ws) {
    __shared__ float s_x[64];
    __shared__ float s_y[64];
    __shared__ float s_sx;
    __shared__ unsigned long long s_min[4];
    __shared__ int s_w;

    int count = *(const int*)(ws + CNT_OFF);
    if (count > LIST_CAP) count = LIST_CAP;
    const int* list = (const int*)(ws + LIST_OFF);
    const float* seg = (const float*)(ws + SE_OFF);
    const int t = threadIdx.x, lane = t & 63, wid = t >> 6;

    for (int i = blockIdx.x; i < count; i += gridDim.x) {
        int n = list[i];
        int bb = n >> 12, hw = n & (HW - 1);
        const float* xin = in + (size_t)bb * (D * HW) + hw;
        if (t < 64) {
            float xv = xin[(size_t)t * HW];
            s_x[t] = xv;
            s_y[t] = __fadd_rn(xv, xv);     // 2x exact
        }
        __syncthreads();
        if (t == 0) s_sx = np_sumsq64(s_x);
        __syncthreads();
        float sx = s_sx;

        // 4 codes per thread, interleaved exact sequential-d chains
        int k0 = t * 4;
        const float* e0 = cb + (size_t)(k0 + 0) * D;
        const float* e1 = cb + (size_t)(k0 + 1) * D;
        const float* e2 = cb + (size_t)(k0 + 2) * D;
        const float* e3 = cb + (size_t)(k0 + 3) * D;
        float a0 = 0.f, a1 = 0.f, a2 = 0.f, a3 = 0.f;
#pragma unroll
        for (int d = 0; d < D; ++d) {
            float yd = s_y[d];
            a0 = __fmaf_rn(yd, e0[d], a0);
            a1 = __fmaf_rn(yd, e1[d], a1);
            a2 = __fmaf_rn(yd, e2[d], a2);
            a3 = __fmaf_rn(yd, e3[d], a3);
        }
        float d0 = __fsub_rn(__fadd_rn(sx, seg[k0 + 0]), a0);
        float d1 = __fsub_rn(__fadd_rn(sx, seg[k0 + 1]), a1);
        float d2 = __fsub_rn(__fadd_rn(sx, seg[k0 + 2]), a2);
        float d3 = __fsub_rn(__fadd_rn(sx, seg[k0 + 3]), a3);
        // dists are positive floats -> bits monotone; pack with code for ties
        unsigned long long q0 = ((unsigned long long)__float_as_uint(d0) << 10) | (k0 + 0);
        unsigned long long q1 = ((unsigned long long)__float_as_uint(d1) << 10) | (k0 + 1);
        unsigned long long q2 = ((unsigned long long)__float_as_uint(d2) << 10) | (k0 + 2);
        unsigned long long q3 = ((unsigned long long)__float_as_uint(d3) << 10) | (k0 + 3);
        unsigned long long best = q0 < q1 ? q0 : q1;
        best = q2 < best ? q2 : best;
        best = q3 < best ? q3 : best;
#pragma unroll
        for (int m = 1; m < 64; m <<= 1) {
            unsigned long long o = __shfl_xor(best, m, 64);
            best = o < best ? o : best;
        }
        if (lane == 0) s_min[wid] = best;
        __syncthreads();
        if (t == 0) {
            unsigned long long bmin = s_min[0];
#pragma unroll
            for (int j = 1; j < 4; ++j) bmin = s_min[j] < bmin ? s_min[j] : bmin;
            s_w = (int)(bmin & 1023u);
        }
        __syncthreads();
        int widx = s_w;
        if (t < 64) out[(size_t)bb * (D * HW) + (size_t)t * HW + hw] = cb[(size_t)widx * D + t];
        __syncthreads();   // s_x/s_y reuse next iteration
    }
}

extern "C" void kernel_launch(void* const* d_in, const int* in_sizes, int n_in,
                              void* d_out, int out_size, void* d_ws, size_t ws_size,
                              hipStream_t stream) {
    const float* in = (const float*)d_in[0];
    const float* cb = (const float*)d_in[1];
    float* out = (float*)d_out;
    char* ws = (char*)d_ws;

    if (ws_size < (size_t)WS_NEED) return;   // fail visibly, never OOB

    prep_cb<<<dim3(K / 256), dim3(256), 0, stream>>>(cb, ws);
    vq_main<<<dim3(NTOTAL / 256), dim3(256), 0, stream>>>(in, cb, out, ws);
    vq_rescore<<<dim3(4096), dim3(256), 0, stream>>>(in, cb, out, ws);
}